// Round 1
// baseline (703.627 us; speedup 1.0000x reference)
//
#include <hip/hip_runtime.h>
#include <hip/hip_bf16.h>
#include <math.h>

#define IN_CH 128
#define HID 64
#define HEADS 4
#define C1 (HEADS*HID)   // 256
#define OUT_CH 64

__device__ __forceinline__ float lrelu(float x){ return x > 0.f ? x : 0.2f*x; }

__device__ __forceinline__ float wsum64(float v){
  #pragma unroll
  for (int m = 32; m >= 1; m >>= 1) v += __shfl_xor(v, m, 64);
  return v;
}
__device__ __forceinline__ float wmax64(float v){
  #pragma unroll
  for (int m = 32; m >= 1; m >>= 1) v = fmaxf(v, __shfl_xor(v, m, 64));
  return v;
}

// ---------------- CSR build ----------------

__global__ void k_zero(int* a, int* b, int n){
  int i = blockIdx.x*256 + threadIdx.x;
  if (i < n){ a[i] = 0; b[i] = 0; }
}

__global__ void k_hist(const int* __restrict__ dst, int* deg, int e){
  int i = blockIdx.x*256 + threadIdx.x;
  if (i < e) atomicAdd(&deg[dst[i]], 1);
}

__global__ void k_scan(const int* __restrict__ deg, int* rowptr, int n){
  __shared__ int buf[256];
  __shared__ int carry;
  int tid = threadIdx.x;
  if (tid == 0){ carry = 0; rowptr[0] = 0; }
  __syncthreads();
  for (int base = 0; base < n; base += 256){
    int v = (base + tid < n) ? deg[base + tid] : 0;
    buf[tid] = v;
    __syncthreads();
    for (int off = 1; off < 256; off <<= 1){
      int t = (tid >= off) ? buf[tid - off] : 0;
      __syncthreads();
      buf[tid] += t;
      __syncthreads();
    }
    if (base + tid < n) rowptr[base + tid + 1] = carry + buf[tid];
    __syncthreads();
    if (tid == 0) carry += buf[255];
    __syncthreads();
  }
}

__global__ void k_scatter(const int* __restrict__ src, const int* __restrict__ dst,
                          const int* __restrict__ rowptr, int* cursor, int* csrc, int e){
  int i = blockIdx.x*256 + threadIdx.x;
  if (i < e){
    int d = dst[i];
    int slot = rowptr[d] + atomicAdd(&cursor[d], 1);
    csrc[slot] = src[i];
  }
}

// ---------------- fp32 tiled GEMM: C[M,N] = A[M,K] @ B[K,N] ----------------
// requires K%16==0, N%64==0; M arbitrary.
__global__ __launch_bounds__(256) void k_gemm(const float* __restrict__ A,
    const float* __restrict__ B, float* __restrict__ C, int M, int N, int K){
  int bm = blockIdx.y * 64;
  int bn = blockIdx.x * 64;
  int tid = threadIdx.x;
  int tx = tid & 15, ty = tid >> 4;
  __shared__ float As[16][65];
  __shared__ float Bs[16][64];
  float acc[4][4] = {};
  for (int k0 = 0; k0 < K; k0 += 16){
    {
      int r = tid >> 2;             // 0..63
      int c = (tid & 3) * 4;        // 0,4,8,12
      int gr = bm + r;
      float4 v = make_float4(0.f,0.f,0.f,0.f);
      if (gr < M) v = *(const float4*)(A + (size_t)gr*K + k0 + c);
      As[c+0][r] = v.x; As[c+1][r] = v.y; As[c+2][r] = v.z; As[c+3][r] = v.w;
    }
    {
      int r = tid >> 4;             // 0..15
      int c = (tid & 15) * 4;
      float4 v = *(const float4*)(B + (size_t)(k0 + r)*N + bn + c);
      *(float4*)&Bs[r][c] = v;
    }
    __syncthreads();
    #pragma unroll
    for (int k = 0; k < 16; ++k){
      float a[4], b[4];
      #pragma unroll
      for (int i = 0; i < 4; ++i) a[i] = As[k][ty*4 + i];
      #pragma unroll
      for (int j = 0; j < 4; ++j) b[j] = Bs[k][tx*4 + j];
      #pragma unroll
      for (int i = 0; i < 4; ++i)
        #pragma unroll
        for (int j = 0; j < 4; ++j)
          acc[i][j] += a[i]*b[j];
    }
    __syncthreads();
  }
  #pragma unroll
  for (int i = 0; i < 4; ++i){
    int gr = bm + ty*4 + i;
    if (gr < M){
      #pragma unroll
      for (int j = 0; j < 4; ++j)
        C[(size_t)gr*N + bn + tx*4 + j] = acc[i][j];
    }
  }
}

// ---------------- attention scalars ----------------
// conv1: block 256 = one node, wave = head
__global__ void k_att1(const float* __restrict__ h, const float* __restrict__ asv,
                       const float* __restrict__ adv, float* as_o, float* ad_o, int n){
  int i = blockIdx.x;
  int t = threadIdx.x;
  float v = h[(size_t)i*C1 + t];
  float ps = wsum64(v * asv[t]);
  float pd = wsum64(v * adv[t]);
  if ((t & 63) == 0){ as_o[i*4 + (t>>6)] = ps; ad_o[i*4 + (t>>6)] = pd; }
}

// conv2: heads=1, 64 ch; block 256 = 4 nodes
__global__ void k_att2(const float* __restrict__ h, const float* __restrict__ asv,
                       const float* __restrict__ adv, float* as_o, float* ad_o, int n){
  int i = blockIdx.x*4 + (threadIdx.x >> 6);
  int lane = threadIdx.x & 63;
  if (i >= n) return;
  float v = h[(size_t)i*OUT_CH + lane];
  float ps = wsum64(v * asv[lane]);
  float pd = wsum64(v * adv[lane]);
  if (lane == 0){ as_o[i] = ps; ad_o[i] = pd; }
}

// ---------------- conv1 aggregation: block 256 = one node ----------------
__global__ __launch_bounds__(256) void k_agg1(
    const float* __restrict__ h1, const float* __restrict__ as1,
    const float* __restrict__ ad1, const int* __restrict__ rowptr,
    const int* __restrict__ csrc, const float* __restrict__ b1,
    float* __restrict__ z1, int n){
  int i = blockIdx.x;
  int tid = threadIdx.x;
  int wv = tid >> 6;      // head in phase A
  int lane = tid & 63;
  __shared__ float s_m[4], s_rd[4], s_adh[4], s_wself[4];
  __shared__ int   s_src[256];
  __shared__ float s_w[4][256];
  int beg = rowptr[i], end = rowptr[i+1];

  // phase A: per-head max + denom over incoming edges + self loop
  {
    float adh = ad1[i*4 + wv];
    float aself = lrelu(as1[i*4 + wv] + adh);
    float mx = aself;
    for (int e = beg + lane; e < end; e += 64){
      int s = csrc[e];
      mx = fmaxf(mx, lrelu(as1[s*4 + wv] + adh));
    }
    mx = wmax64(mx);
    float sm = 0.f;
    for (int e = beg + lane; e < end; e += 64){
      int s = csrc[e];
      sm += expf(lrelu(as1[s*4 + wv] + adh) - mx);
    }
    sm = wsum64(sm);
    sm += expf(aself - mx);
    float rd = 1.f / (sm + 1e-16f);
    if (lane == 0){
      s_m[wv] = mx; s_rd[wv] = rd; s_adh[wv] = adh;
      s_wself[wv] = expf(aself - mx) * rd;
    }
  }
  __syncthreads();

  // phase B: weighted accumulation; thread owns channel tid, head = tid>>6
  int hc = tid >> 6;
  float acc = s_wself[hc] * h1[(size_t)i*C1 + tid];
  for (int cs = beg; cs < end; cs += 256){
    int cn = min(256, end - cs);
    __syncthreads();
    if (tid < cn){
      int s = csrc[cs + tid];
      s_src[tid] = s;
      #pragma unroll
      for (int h = 0; h < 4; ++h)
        s_w[h][tid] = expf(lrelu(as1[s*4 + h] + s_adh[h]) - s_m[h]) * s_rd[h];
    }
    __syncthreads();
    for (int e = 0; e < cn; ++e)
      acc += s_w[hc][e] * h1[(size_t)s_src[e]*C1 + tid];
  }
  z1[(size_t)i*C1 + tid] = fmaxf(acc + b1[tid], 0.f);   // + bias, relu
}

// ---------------- conv2 aggregation: block 64 (one wave) = one node ----------------
__global__ __launch_bounds__(64) void k_agg2(
    const float* __restrict__ h2, const float* __restrict__ as2,
    const float* __restrict__ ad2, const int* __restrict__ rowptr,
    const int* __restrict__ csrc, const float* __restrict__ b2,
    float* __restrict__ z2, int n){
  int i = blockIdx.x;
  int t = threadIdx.x;   // 0..63
  __shared__ int   s_src[64];
  __shared__ float s_w[64];
  int beg = rowptr[i], end = rowptr[i+1];
  float adv = ad2[i];
  float aself = lrelu(as2[i] + adv);
  float mx = aself;
  for (int e = beg + t; e < end; e += 64)
    mx = fmaxf(mx, lrelu(as2[csrc[e]] + adv));
  mx = wmax64(mx);
  float sm = 0.f;
  for (int e = beg + t; e < end; e += 64)
    sm += expf(lrelu(as2[csrc[e]] + adv) - mx);
  sm = wsum64(sm) + expf(aself - mx);
  float rd = 1.f / (sm + 1e-16f);
  float acc = (expf(aself - mx) * rd) * h2[(size_t)i*OUT_CH + t];
  for (int cs = beg; cs < end; cs += 64){
    int cn = min(64, end - cs);
    __syncthreads();
    if (t < cn){
      int s = csrc[cs + t];
      s_src[t] = s;
      s_w[t] = expf(lrelu(as2[s] + adv) - mx) * rd;
    }
    __syncthreads();
    for (int e = 0; e < cn; ++e)
      acc += s_w[e] * h2[(size_t)s_src[e]*OUT_CH + t];
  }
  z2[(size_t)i*OUT_CH + t] = acc + b2[t];   // + bias, no relu
}

// ---------------- decoder: 16 lanes per edge, dot over 64 ch ----------------
__global__ void k_decode(const float* __restrict__ z2, const int* __restrict__ pos,
                         const int* __restrict__ neg, float* __restrict__ out, int e){
  int g = blockIdx.x*256 + threadIdx.x;
  int k = g >> 4;
  int sub = g & 15;
  if (k >= 2*e) return;
  int a, b;
  if (k < e){ a = pos[k];     b = pos[e + k]; }
  else      { a = neg[k - e]; b = neg[e + (k - e)]; }
  const float4* ra = (const float4*)(z2 + (size_t)a*OUT_CH);
  const float4* rb = (const float4*)(z2 + (size_t)b*OUT_CH);
  float4 xa = ra[sub], xb = rb[sub];
  float s = xa.x*xb.x + xa.y*xb.y + xa.z*xb.z + xa.w*xb.w;
  #pragma unroll
  for (int m = 8; m >= 1; m >>= 1) s += __shfl_xor(s, m, 64);
  if (sub == 0) out[k] = s;
}

extern "C" void kernel_launch(void* const* d_in, const int* in_sizes, int n_in,
                              void* d_out, int out_size, void* d_ws, size_t ws_size,
                              hipStream_t stream) {
  const float* x        = (const float*)d_in[0];
  const int*   pos      = (const int*)d_in[1];
  const int*   neg      = (const int*)d_in[2];
  const float* W1       = (const float*)d_in[3];
  const float* att_src1 = (const float*)d_in[4];
  const float* att_dst1 = (const float*)d_in[5];
  const float* b1       = (const float*)d_in[6];
  const float* W2       = (const float*)d_in[7];
  const float* att_src2 = (const float*)d_in[8];
  const float* att_dst2 = (const float*)d_in[9];
  const float* b2       = (const float*)d_in[10];
  float* out = (float*)d_out;

  const int N = in_sizes[0] / IN_CH;   // 50000
  const int E = in_sizes[1] / 2;       // 800000

  char* w = (char*)d_ws;
  float* h1  = (float*)w;  w += (size_t)N*C1*4;
  float* z1v = (float*)w;  w += (size_t)N*C1*4;
  float* h2  = (float*)w;  w += (size_t)N*OUT_CH*4;
  float* z2v = (float*)w;  w += (size_t)N*OUT_CH*4;
  float* as1 = (float*)w;  w += (size_t)N*4*4;
  float* ad1 = (float*)w;  w += (size_t)N*4*4;
  float* as2 = (float*)w;  w += (size_t)N*4;
  float* ad2 = (float*)w;  w += (size_t)N*4;
  int* deg    = (int*)w;   w += (size_t)N*4;
  int* rowptr = (int*)w;   w += (size_t)(N+1)*4;
  int* cursor = (int*)w;   w += (size_t)N*4;
  int* csrc   = (int*)w;   w += (size_t)E*4;

  int eb = (E + 255)/256;
  const int* pdst = pos + E;   // edge_index[1]

  k_zero<<<(N + 255)/256, 256, 0, stream>>>(deg, cursor, N);
  k_hist<<<eb, 256, 0, stream>>>(pdst, deg, E);
  k_scan<<<1, 256, 0, stream>>>(deg, rowptr, N);
  k_scatter<<<eb, 256, 0, stream>>>(pos, pdst, rowptr, cursor, csrc, E);

  dim3 g1((C1 + 63)/64, (N + 63)/64);
  k_gemm<<<g1, 256, 0, stream>>>(x, W1, h1, N, C1, IN_CH);
  k_att1<<<N, 256, 0, stream>>>(h1, att_src1, att_dst1, as1, ad1, N);
  k_agg1<<<N, 256, 0, stream>>>(h1, as1, ad1, rowptr, csrc, b1, z1v, N);

  dim3 g2((OUT_CH + 63)/64, (N + 63)/64);
  k_gemm<<<g2, 256, 0, stream>>>(z1v, W2, h2, N, OUT_CH, C1);
  k_att2<<<(N + 3)/4, 256, 0, stream>>>(h2, att_src2, att_dst2, as2, ad2, N);
  k_agg2<<<N, 64, 0, stream>>>(h2, as2, ad2, rowptr, csrc, b2, z2v, N);

  k_decode<<<((size_t)2*E*16 + 255)/256, 256, 0, stream>>>(z2v, pos, neg, out, E);
}

// Round 2
// 501.389 us; speedup vs baseline: 1.4034x; 1.4034x over previous
//
#include <hip/hip_runtime.h>
#include <hip/hip_bf16.h>
#include <math.h>

#define IN_CH 128
#define HID 64
#define HEADS 4
#define C1 (HEADS*HID)   // 256
#define OUT_CH 64

__device__ __forceinline__ float lrelu(float x){ return x > 0.f ? x : 0.2f*x; }

__device__ __forceinline__ float wsum64(float v){
  #pragma unroll
  for (int m = 32; m >= 1; m >>= 1) v += __shfl_xor(v, m, 64);
  return v;
}
__device__ __forceinline__ float wmax64(float v){
  #pragma unroll
  for (int m = 32; m >= 1; m >>= 1) v = fmaxf(v, __shfl_xor(v, m, 64));
  return v;
}

// ---------------- CSR build ----------------

__global__ void k_zero(int* a, int* b, int n){
  int i = blockIdx.x*256 + threadIdx.x;
  if (i < n){ a[i] = 0; b[i] = 0; }
}

__global__ void k_hist(const int* __restrict__ dst, int* deg, int e){
  int i = blockIdx.x*256 + threadIdx.x;
  if (i < e) atomicAdd(&deg[dst[i]], 1);
}

// hierarchical scan: per-block reduce -> scan block sums -> per-block scan
__global__ void k_blocksum(const int* __restrict__ deg, int* bsum, int n){
  __shared__ int buf[256];
  int b = blockIdx.x, tid = threadIdx.x;
  int i = b*256 + tid;
  buf[tid] = (i < n) ? deg[i] : 0;
  __syncthreads();
  for (int off = 128; off > 0; off >>= 1){
    if (tid < off) buf[tid] += buf[tid + off];
    __syncthreads();
  }
  if (tid == 0) bsum[b] = buf[0];
}

__global__ void k_scanb(int* bsum, int nb){   // exclusive scan in place (nb <= 256)
  __shared__ int buf[256];
  int tid = threadIdx.x;
  int v = (tid < nb) ? bsum[tid] : 0;
  buf[tid] = v;
  __syncthreads();
  for (int off = 1; off < 256; off <<= 1){
    int t = (tid >= off) ? buf[tid - off] : 0;
    __syncthreads();
    buf[tid] += t;
    __syncthreads();
  }
  if (tid < nb) bsum[tid] = buf[tid] - v;
}

__global__ void k_scanfinal(const int* __restrict__ deg, const int* __restrict__ bsum,
                            int* rowptr, int n){
  __shared__ int buf[256];
  int b = blockIdx.x, tid = threadIdx.x;
  int i = b*256 + tid;
  int v = (i < n) ? deg[i] : 0;
  buf[tid] = v;
  __syncthreads();
  for (int off = 1; off < 256; off <<= 1){
    int t = (tid >= off) ? buf[tid - off] : 0;
    __syncthreads();
    buf[tid] += t;
    __syncthreads();
  }
  if (i < n) rowptr[i + 1] = bsum[b] + buf[tid];
  if (b == 0 && tid == 0) rowptr[0] = 0;
}

__global__ void k_scatter(const int* __restrict__ src, const int* __restrict__ dst,
                          const int* __restrict__ rowptr, int* cursor, int* csrc, int e){
  int i = blockIdx.x*256 + threadIdx.x;
  if (i < e){
    int d = dst[i];
    int slot = rowptr[d] + atomicAdd(&cursor[d], 1);
    csrc[slot] = src[i];
  }
}

// ---------------- fp32 tiled GEMM: C[M,N] = A[M,K] @ B[K,N] ----------------
// requires K%16==0, N%64==0; M arbitrary.
__global__ __launch_bounds__(256) void k_gemm(const float* __restrict__ A,
    const float* __restrict__ B, float* __restrict__ C, int M, int N, int K){
  int bm = blockIdx.y * 64;
  int bn = blockIdx.x * 64;
  int tid = threadIdx.x;
  int tx = tid & 15, ty = tid >> 4;
  __shared__ float As[16][65];
  __shared__ float Bs[16][64];
  float acc[4][4] = {};
  for (int k0 = 0; k0 < K; k0 += 16){
    {
      int r = tid >> 2;             // 0..63
      int c = (tid & 3) * 4;        // 0,4,8,12
      int gr = bm + r;
      float4 v = make_float4(0.f,0.f,0.f,0.f);
      if (gr < M) v = *(const float4*)(A + (size_t)gr*K + k0 + c);
      As[c+0][r] = v.x; As[c+1][r] = v.y; As[c+2][r] = v.z; As[c+3][r] = v.w;
    }
    {
      int r = tid >> 4;             // 0..15
      int c = (tid & 15) * 4;
      float4 v = *(const float4*)(B + (size_t)(k0 + r)*N + bn + c);
      *(float4*)&Bs[r][c] = v;
    }
    __syncthreads();
    #pragma unroll
    for (int k = 0; k < 16; ++k){
      float a[4], b[4];
      #pragma unroll
      for (int i = 0; i < 4; ++i) a[i] = As[k][ty*4 + i];
      #pragma unroll
      for (int j = 0; j < 4; ++j) b[j] = Bs[k][tx*4 + j];
      #pragma unroll
      for (int i = 0; i < 4; ++i)
        #pragma unroll
        for (int j = 0; j < 4; ++j)
          acc[i][j] += a[i]*b[j];
    }
    __syncthreads();
  }
  #pragma unroll
  for (int i = 0; i < 4; ++i){
    int gr = bm + ty*4 + i;
    if (gr < M){
      #pragma unroll
      for (int j = 0; j < 4; ++j)
        C[(size_t)gr*N + bn + tx*4 + j] = acc[i][j];
    }
  }
}

// ---------------- attention scalars ----------------
// conv1: block 256 = one node, wave = head
__global__ void k_att1(const float* __restrict__ h, const float* __restrict__ asv,
                       const float* __restrict__ adv, float* as_o, float* ad_o, int n){
  int i = blockIdx.x;
  int t = threadIdx.x;
  float v = h[(size_t)i*C1 + t];
  float ps = wsum64(v * asv[t]);
  float pd = wsum64(v * adv[t]);
  if ((t & 63) == 0){ as_o[i*4 + (t>>6)] = ps; ad_o[i*4 + (t>>6)] = pd; }
}

// conv2: heads=1, 64 ch; block 256 = 4 nodes
__global__ void k_att2(const float* __restrict__ h, const float* __restrict__ asv,
                       const float* __restrict__ adv, float* as_o, float* ad_o, int n){
  int i = blockIdx.x*4 + (threadIdx.x >> 6);
  int lane = threadIdx.x & 63;
  if (i >= n) return;
  float v = h[(size_t)i*OUT_CH + lane];
  float ps = wsum64(v * asv[lane]);
  float pd = wsum64(v * adv[lane]);
  if (lane == 0){ as_o[i] = ps; ad_o[i] = pd; }
}

// ---------------- conv1 aggregation: block 256 = one node ----------------
__global__ __launch_bounds__(256) void k_agg1(
    const float* __restrict__ h1, const float* __restrict__ as1,
    const float* __restrict__ ad1, const int* __restrict__ rowptr,
    const int* __restrict__ csrc, const float* __restrict__ b1,
    float* __restrict__ z1, int n){
  int i = blockIdx.x;
  int tid = threadIdx.x;
  int wv = tid >> 6;      // head in phase A
  int lane = tid & 63;
  __shared__ float s_m[4], s_rd[4], s_adh[4], s_wself[4];
  __shared__ int   s_src[256];
  __shared__ float s_w[4][256];
  int beg = rowptr[i], end = rowptr[i+1];

  // phase A: per-head max + denom over incoming edges + self loop
  {
    float adh = ad1[i*4 + wv];
    float aself = lrelu(as1[i*4 + wv] + adh);
    float mx = aself;
    for (int e = beg + lane; e < end; e += 64){
      int s = csrc[e];
      mx = fmaxf(mx, lrelu(as1[s*4 + wv] + adh));
    }
    mx = wmax64(mx);
    float sm = 0.f;
    for (int e = beg + lane; e < end; e += 64){
      int s = csrc[e];
      sm += expf(lrelu(as1[s*4 + wv] + adh) - mx);
    }
    sm = wsum64(sm);
    sm += expf(aself - mx);
    float rd = 1.f / (sm + 1e-16f);
    if (lane == 0){
      s_m[wv] = mx; s_rd[wv] = rd; s_adh[wv] = adh;
      s_wself[wv] = expf(aself - mx) * rd;
    }
  }
  __syncthreads();

  // phase B: weighted accumulation; thread owns channel tid, head = tid>>6
  int hc = tid >> 6;
  float acc = s_wself[hc] * h1[(size_t)i*C1 + tid];
  for (int cs = beg; cs < end; cs += 256){
    int cn = min(256, end - cs);
    __syncthreads();
    if (tid < cn){
      int s = csrc[cs + tid];
      s_src[tid] = s;
      #pragma unroll
      for (int h = 0; h < 4; ++h)
        s_w[h][tid] = expf(lrelu(as1[s*4 + h] + s_adh[h]) - s_m[h]) * s_rd[h];
    }
    __syncthreads();
    for (int e = 0; e < cn; ++e)
      acc += s_w[hc][e] * h1[(size_t)s_src[e]*C1 + tid];
  }
  z1[(size_t)i*C1 + tid] = fmaxf(acc + b1[tid], 0.f);   // + bias, relu
}

// ---------------- conv2 aggregation: block 64 (one wave) = one node ----------------
__global__ __launch_bounds__(64) void k_agg2(
    const float* __restrict__ h2, const float* __restrict__ as2,
    const float* __restrict__ ad2, const int* __restrict__ rowptr,
    const int* __restrict__ csrc, const float* __restrict__ b2,
    float* __restrict__ z2, int n){
  int i = blockIdx.x;
  int t = threadIdx.x;   // 0..63
  __shared__ int   s_src[64];
  __shared__ float s_w[64];
  int beg = rowptr[i], end = rowptr[i+1];
  float adv = ad2[i];
  float aself = lrelu(as2[i] + adv);
  float mx = aself;
  for (int e = beg + t; e < end; e += 64)
    mx = fmaxf(mx, lrelu(as2[csrc[e]] + adv));
  mx = wmax64(mx);
  float sm = 0.f;
  for (int e = beg + t; e < end; e += 64)
    sm += expf(lrelu(as2[csrc[e]] + adv) - mx);
  sm = wsum64(sm) + expf(aself - mx);
  float rd = 1.f / (sm + 1e-16f);
  float acc = (expf(aself - mx) * rd) * h2[(size_t)i*OUT_CH + t];
  for (int cs = beg; cs < end; cs += 64){
    int cn = min(64, end - cs);
    __syncthreads();
    if (t < cn){
      int s = csrc[cs + t];
      s_src[t] = s;
      s_w[t] = expf(lrelu(as2[s] + adv) - mx) * rd;
    }
    __syncthreads();
    for (int e = 0; e < cn; ++e)
      acc += s_w[e] * h2[(size_t)s_src[e]*OUT_CH + t];
  }
  z2[(size_t)i*OUT_CH + t] = acc + b2[t];   // + bias, no relu
}

// ---------------- decoder: 16 lanes per edge, dot over 64 ch ----------------
__global__ void k_decode(const float* __restrict__ z2, const int* __restrict__ pos,
                         const int* __restrict__ neg, float* __restrict__ out, int e){
  int g = blockIdx.x*256 + threadIdx.x;
  int k = g >> 4;
  int sub = g & 15;
  if (k >= 2*e) return;
  int a, b;
  if (k < e){ a = pos[k];     b = pos[e + k]; }
  else      { a = neg[k - e]; b = neg[e + (k - e)]; }
  const float4* ra = (const float4*)(z2 + (size_t)a*OUT_CH);
  const float4* rb = (const float4*)(z2 + (size_t)b*OUT_CH);
  float4 xa = ra[sub], xb = rb[sub];
  float s = xa.x*xb.x + xa.y*xb.y + xa.z*xb.z + xa.w*xb.w;
  #pragma unroll
  for (int m = 8; m >= 1; m >>= 1) s += __shfl_xor(s, m, 64);
  if (sub == 0) out[k] = s;
}

extern "C" void kernel_launch(void* const* d_in, const int* in_sizes, int n_in,
                              void* d_out, int out_size, void* d_ws, size_t ws_size,
                              hipStream_t stream) {
  const float* x        = (const float*)d_in[0];
  const int*   pos      = (const int*)d_in[1];
  const int*   neg      = (const int*)d_in[2];
  const float* W1       = (const float*)d_in[3];
  const float* att_src1 = (const float*)d_in[4];
  const float* att_dst1 = (const float*)d_in[5];
  const float* b1       = (const float*)d_in[6];
  const float* W2       = (const float*)d_in[7];
  const float* att_src2 = (const float*)d_in[8];
  const float* att_dst2 = (const float*)d_in[9];
  const float* b2       = (const float*)d_in[10];
  float* out = (float*)d_out;

  const int N = in_sizes[0] / IN_CH;   // 50000
  const int E = in_sizes[1] / 2;       // 800000

  char* w = (char*)d_ws;
  float* h1  = (float*)w;  w += (size_t)N*C1*4;
  float* z1v = (float*)w;  w += (size_t)N*C1*4;
  float* h2  = (float*)w;  w += (size_t)N*OUT_CH*4;
  float* z2v = (float*)w;  w += (size_t)N*OUT_CH*4;
  float* as1 = (float*)w;  w += (size_t)N*4*4;
  float* ad1 = (float*)w;  w += (size_t)N*4*4;
  float* as2 = (float*)w;  w += (size_t)N*4;
  float* ad2 = (float*)w;  w += (size_t)N*4;
  int* deg    = (int*)w;   w += (size_t)N*4;
  int* rowptr = (int*)w;   w += (size_t)(N+1)*4;
  int* cursor = (int*)w;   w += (size_t)N*4;
  int* bsum   = (int*)w;   w += (size_t)256*4;
  int* csrc   = (int*)w;   w += (size_t)E*4;

  int eb = (E + 255)/256;
  int nb = (N + 255)/256;   // 196 blocks
  const int* pdst = pos + E;   // edge_index[1]

  k_zero<<<nb, 256, 0, stream>>>(deg, cursor, N);
  k_hist<<<eb, 256, 0, stream>>>(pdst, deg, E);
  k_blocksum<<<nb, 256, 0, stream>>>(deg, bsum, N);
  k_scanb<<<1, 256, 0, stream>>>(bsum, nb);
  k_scanfinal<<<nb, 256, 0, stream>>>(deg, bsum, rowptr, N);
  k_scatter<<<eb, 256, 0, stream>>>(pos, pdst, rowptr, cursor, csrc, E);

  dim3 g1((C1 + 63)/64, (N + 63)/64);
  k_gemm<<<g1, 256, 0, stream>>>(x, W1, h1, N, C1, IN_CH);
  k_att1<<<N, 256, 0, stream>>>(h1, att_src1, att_dst1, as1, ad1, N);
  k_agg1<<<N, 256, 0, stream>>>(h1, as1, ad1, rowptr, csrc, b1, z1v, N);

  dim3 g2((OUT_CH + 63)/64, (N + 63)/64);
  k_gemm<<<g2, 256, 0, stream>>>(z1v, W2, h2, N, OUT_CH, C1);
  k_att2<<<(N + 3)/4, 256, 0, stream>>>(h2, att_src2, att_dst2, as2, ad2, N);
  k_agg2<<<N, 64, 0, stream>>>(h2, as2, ad2, rowptr, csrc, b2, z2v, N);

  k_decode<<<((size_t)2*E*16 + 255)/256, 256, 0, stream>>>(z2v, pos, neg, out, E);
}

// Round 3
// 479.053 us; speedup vs baseline: 1.4688x; 1.0466x over previous
//
#include <hip/hip_runtime.h>
#include <hip/hip_bf16.h>
#include <math.h>

#define IN_CH 128
#define HID 64
#define HEADS 4
#define C1 (HEADS*HID)   // 256
#define OUT_CH 64

typedef __attribute__((ext_vector_type(8))) short short8v;
typedef __attribute__((ext_vector_type(4))) float f32x4;

__device__ __forceinline__ float lrelu(float x){ return x > 0.f ? x : 0.2f*x; }

__device__ __forceinline__ ushort f2b(float f){
  unsigned u = __builtin_bit_cast(unsigned, f);
  unsigned r = (u + 0x7FFF + ((u>>16)&1)) >> 16;
  return (ushort)r;
}
__device__ __forceinline__ float b2f(ushort b){
  unsigned u = ((unsigned)b) << 16;
  return __builtin_bit_cast(float, u);
}

__device__ __forceinline__ float wsum64(float v){
  #pragma unroll
  for (int m = 32; m >= 1; m >>= 1) v += __shfl_xor(v, m, 64);
  return v;
}
__device__ __forceinline__ float wmax64(float v){
  #pragma unroll
  for (int m = 32; m >= 1; m >>= 1) v = fmaxf(v, __shfl_xor(v, m, 64));
  return v;
}

// ---------------- CSR build ----------------

__global__ void k_zero(int* a, int* b, int n){
  int i = blockIdx.x*256 + threadIdx.x;
  if (i < n){ a[i] = 0; b[i] = 0; }
}

__global__ void k_hist(const int* __restrict__ dst, int* deg, int e){
  int i = blockIdx.x*256 + threadIdx.x;
  if (i < e) atomicAdd(&deg[dst[i]], 1);
}

__global__ void k_blocksum(const int* __restrict__ deg, int* bsum, int n){
  __shared__ int buf[256];
  int b = blockIdx.x, tid = threadIdx.x;
  int i = b*256 + tid;
  buf[tid] = (i < n) ? deg[i] : 0;
  __syncthreads();
  for (int off = 128; off > 0; off >>= 1){
    if (tid < off) buf[tid] += buf[tid + off];
    __syncthreads();
  }
  if (tid == 0) bsum[b] = buf[0];
}

__global__ void k_scanb(int* bsum, int nb){   // exclusive scan in place (nb <= 256)
  __shared__ int buf[256];
  int tid = threadIdx.x;
  int v = (tid < nb) ? bsum[tid] : 0;
  buf[tid] = v;
  __syncthreads();
  for (int off = 1; off < 256; off <<= 1){
    int t = (tid >= off) ? buf[tid - off] : 0;
    __syncthreads();
    buf[tid] += t;
    __syncthreads();
  }
  if (tid < nb) bsum[tid] = buf[tid] - v;
}

__global__ void k_scanfinal(const int* __restrict__ deg, const int* __restrict__ bsum,
                            int* rowptr, int n){
  __shared__ int buf[256];
  int b = blockIdx.x, tid = threadIdx.x;
  int i = b*256 + tid;
  int v = (i < n) ? deg[i] : 0;
  buf[tid] = v;
  __syncthreads();
  for (int off = 1; off < 256; off <<= 1){
    int t = (tid >= off) ? buf[tid - off] : 0;
    __syncthreads();
    buf[tid] += t;
    __syncthreads();
  }
  if (i < n) rowptr[i + 1] = bsum[b] + buf[tid];
  if (b == 0 && tid == 0) rowptr[0] = 0;
}

__global__ void k_scatter(const int* __restrict__ src, const int* __restrict__ dst,
                          const int* __restrict__ rowptr, int* cursor, int* csrc, int e){
  int i = blockIdx.x*256 + threadIdx.x;
  if (i < e){
    int d = dst[i];
    int slot = rowptr[d] + atomicAdd(&cursor[d], 1);
    csrc[slot] = src[i];
  }
}

// ---------------- casts ----------------

__global__ void k_castx(const float4* __restrict__ in, ushort* __restrict__ out, int n4){
  int i = blockIdx.x*256 + threadIdx.x;
  if (i < n4){
    float4 v = in[i];
    ushort4 o;
    o.x = f2b(v.x); o.y = f2b(v.y); o.z = f2b(v.z); o.w = f2b(v.w);
    *(ushort4*)(out + (size_t)i*4) = o;
  }
}

// W [K][N] f32 -> Wt [N][K] bf16
__global__ void k_tw(const float* __restrict__ W, ushort* __restrict__ Wt, int K, int N){
  int i = blockIdx.x*256 + threadIdx.x;
  if (i < K*N){
    int k = i / N, c = i - k*N;
    Wt[(size_t)c*K + k] = f2b(W[i]);
  }
}

// ---------------- bf16 MFMA GEMM: C[M,N] = A[M,K] @ Bt[N,K]^T ----------------
// BM=128, BK=64, 4 waves (2x2). BN = 128 or 64. K % 64 == 0.
template<int BN>
__global__ __launch_bounds__(256) void k_gemm_bf16(
    const ushort* __restrict__ A, const ushort* __restrict__ Bt,
    ushort* __restrict__ Cb, int M, int N, int K)
{
  constexpr int BM = 128;
  constexpr int NF = BN / 32;          // N-fragments per wave
  __shared__ uint4 As[BM*8];
  __shared__ uint4 Bs[BN*8];
  int tid = threadIdx.x;
  int wave = tid >> 6, lane = tid & 63;
  int wr = wave >> 1, wc = wave & 1;
  int bm = blockIdx.y * BM;
  int bn = blockIdx.x * BN;
  int g = lane >> 4, lr = lane & 15;

  f32x4 acc[4][NF];
  #pragma unroll
  for (int m = 0; m < 4; ++m)
    #pragma unroll
    for (int n = 0; n < NF; ++n) acc[m][n] = (f32x4)(0.f);

  for (int k0 = 0; k0 < K; k0 += 64){
    for (int idx = tid; idx < BM*8; idx += 256){
      int r = idx >> 3, c = idx & 7;
      int gr = bm + r;
      uint4 v = make_uint4(0u,0u,0u,0u);
      if (gr < M) v = *(const uint4*)(A + (size_t)gr*K + k0 + c*8);
      As[r*8 + (c ^ (r & 7))] = v;
    }
    for (int idx = tid; idx < BN*8; idx += 256){
      int r = idx >> 3, c = idx & 7;
      uint4 v = *(const uint4*)(Bt + (size_t)(bn + r)*K + k0 + c*8);
      Bs[r*8 + (c ^ (r & 7))] = v;
    }
    __syncthreads();
    #pragma unroll
    for (int kk = 0; kk < 2; ++kk){
      short8v af[4], bf[NF];
      #pragma unroll
      for (int m = 0; m < 4; ++m){
        int r = wr*64 + m*16 + lr;
        int c = kk*4 + g;
        af[m] = *(const short8v*)&As[r*8 + (c ^ (r & 7))];
      }
      #pragma unroll
      for (int n = 0; n < NF; ++n){
        int r = wc*(BN/2) + n*16 + lr;
        int c = kk*4 + g;
        bf[n] = *(const short8v*)&Bs[r*8 + (c ^ (r & 7))];
      }
      #pragma unroll
      for (int m = 0; m < 4; ++m)
        #pragma unroll
        for (int n = 0; n < NF; ++n)
          acc[m][n] = __builtin_amdgcn_mfma_f32_16x16x32_bf16(af[m], bf[n], acc[m][n], 0, 0, 0);
    }
    __syncthreads();
  }
  #pragma unroll
  for (int m = 0; m < 4; ++m){
    #pragma unroll
    for (int q = 0; q < 4; ++q){
      int row = bm + wr*64 + m*16 + g*4 + q;
      if (row < M){
        #pragma unroll
        for (int n = 0; n < NF; ++n){
          int col = bn + wc*(BN/2) + n*16 + lr;
          Cb[(size_t)row*N + col] = f2b(acc[m][n][q]);
        }
      }
    }
  }
}

// ---------------- attention scalars (read bf16 h) ----------------

__global__ void k_att1(const ushort* __restrict__ h, const float* __restrict__ asv,
                       const float* __restrict__ adv, float* as_o, float* ad_o, int n){
  int i = blockIdx.x;
  int t = threadIdx.x;
  float v = b2f(h[(size_t)i*C1 + t]);
  float ps = wsum64(v * asv[t]);
  float pd = wsum64(v * adv[t]);
  if ((t & 63) == 0){ as_o[i*4 + (t>>6)] = ps; ad_o[i*4 + (t>>6)] = pd; }
}

__global__ void k_att2(const ushort* __restrict__ h, const float* __restrict__ asv,
                       const float* __restrict__ adv, float* as_o, float* ad_o, int n){
  int i = blockIdx.x*4 + (threadIdx.x >> 6);
  int lane = threadIdx.x & 63;
  if (i >= n) return;
  float v = b2f(h[(size_t)i*OUT_CH + lane]);
  float ps = wsum64(v * asv[lane]);
  float pd = wsum64(v * adv[lane]);
  if (lane == 0){ as_o[i] = ps; ad_o[i] = pd; }
}

// ---------------- conv1 aggregation ----------------
// Phase A: one online gather pass over edges (all 4 heads per lane via float4),
// raw alpha stashed to aw[slot]. Phase B: weight staging from linear aw.
__global__ __launch_bounds__(256) void k_agg1(
    const ushort* __restrict__ h1b, const float* __restrict__ as1,
    const float* __restrict__ ad1, const int* __restrict__ rowptr,
    const int* __restrict__ csrc, const float* __restrict__ b1,
    float* __restrict__ aw, __hip_bfloat16* __restrict__ z1b, int n)
{
  int i = blockIdx.x;
  int tid = threadIdx.x;
  int wave = tid >> 6;
  __shared__ float s_M[4][4], s_S[4][4];   // [wave][head]
  __shared__ float s_m[4], s_rd[4], s_wself[4];
  __shared__ int   s_src[256];
  __shared__ float s_w[4][256];
  int beg = rowptr[i], end = rowptr[i+1];
  f32x4 ad4 = *(const f32x4*)(ad1 + 4*i);

  // phase A
  float m[4] = {-1e30f,-1e30f,-1e30f,-1e30f};
  float s[4] = {0.f,0.f,0.f,0.f};
  for (int sl = beg + tid; sl < end; sl += 256){
    int sj = csrc[sl];
    f32x4 a4 = *(const f32x4*)(as1 + 4*sj);
    f32x4 al;
    #pragma unroll
    for (int h = 0; h < 4; ++h){
      float a = lrelu(a4[h] + ad4[h]);
      al[h] = a;
      if (a <= m[h]) s[h] += expf(a - m[h]);
      else { s[h] = s[h]*expf(m[h] - a) + 1.f; m[h] = a; }
    }
    *(f32x4*)(aw + 4*(size_t)sl) = al;
  }
  #pragma unroll
  for (int h = 0; h < 4; ++h){
    float Mw = wmax64(m[h]);
    float Sw = wsum64(s[h] * expf(m[h] - Mw));
    if ((tid & 63) == 0){ s_M[wave][h] = Mw; s_S[wave][h] = Sw; }
  }
  __syncthreads();
  if (tid < 4){
    int h = tid;
    f32x4 asf = *(const f32x4*)(as1 + 4*i);
    float aself = lrelu(asf[h] + ad4[h]);
    float M = aself;
    #pragma unroll
    for (int w = 0; w < 4; ++w) M = fmaxf(M, s_M[w][h]);
    float S = 0.f;
    #pragma unroll
    for (int w = 0; w < 4; ++w) S += s_S[w][h] * expf(s_M[w][h] - M);
    float es = expf(aself - M);
    S += es;
    float rd = 1.f / (S + 1e-16f);
    s_m[h] = M; s_rd[h] = rd; s_wself[h] = es * rd;
  }
  __syncthreads();

  // phase B
  int hc = tid >> 6;
  float acc = s_wself[hc] * b2f(h1b[(size_t)i*C1 + tid]);
  for (int cs = beg; cs < end; cs += 256){
    int cn = min(256, end - cs);
    __syncthreads();
    if (tid < cn){
      s_src[tid] = csrc[cs + tid];
      f32x4 al = *(const f32x4*)(aw + 4*(size_t)(cs + tid));
      #pragma unroll
      for (int h = 0; h < 4; ++h)
        s_w[h][tid] = expf(al[h] - s_m[h]) * s_rd[h];
    }
    __syncthreads();
    for (int e = 0; e < cn; ++e)
      acc += s_w[hc][e] * b2f(h1b[(size_t)s_src[e]*C1 + tid]);
  }
  z1b[(size_t)i*C1 + tid] = __float2bfloat16(fmaxf(acc + b1[tid], 0.f));
}

// ---------------- conv2 aggregation (1 wave per node) ----------------
__global__ __launch_bounds__(64) void k_agg2(
    const ushort* __restrict__ h2b, const float* __restrict__ as2,
    const float* __restrict__ ad2, const int* __restrict__ rowptr,
    const int* __restrict__ csrc, const float* __restrict__ b2,
    float* __restrict__ aw2, float* __restrict__ z2, int n)
{
  int i = blockIdx.x;
  int t = threadIdx.x;
  __shared__ int   s_src[64];
  __shared__ float s_w[64];
  int beg = rowptr[i], end = rowptr[i+1];
  float adv = ad2[i];

  float m = -1e30f, s = 0.f;
  for (int sl = beg + t; sl < end; sl += 64){
    float a = lrelu(as2[csrc[sl]] + adv);
    aw2[sl] = a;
    if (a <= m) s += expf(a - m);
    else { s = s*expf(m - a) + 1.f; m = a; }
  }
  float M = wmax64(m);
  float S = wsum64(s * expf(m - M));
  float aself = lrelu(as2[i] + adv);
  float M2 = fmaxf(M, aself);
  S = S * expf(M - M2);
  float es = expf(aself - M2);
  S += es;
  float rd = 1.f / (S + 1e-16f);

  float acc = es * rd * b2f(h2b[(size_t)i*OUT_CH + t]);
  for (int cs = beg; cs < end; cs += 64){
    int cn = min(64, end - cs);
    __syncthreads();
    if (t < cn){
      s_src[t] = csrc[cs + t];
      s_w[t] = expf(aw2[cs + t] - M2) * rd;
    }
    __syncthreads();
    for (int e = 0; e < cn; ++e)
      acc += s_w[e] * b2f(h2b[(size_t)s_src[e]*OUT_CH + t]);
  }
  z2[(size_t)i*OUT_CH + t] = acc + b2[t];
}

// ---------------- decoder ----------------
__global__ void k_decode(const float* __restrict__ z2, const int* __restrict__ pos,
                         const int* __restrict__ neg, float* __restrict__ out, int e){
  int g = blockIdx.x*256 + threadIdx.x;
  int k = g >> 4;
  int sub = g & 15;
  if (k >= 2*e) return;
  int a, b;
  if (k < e){ a = pos[k];     b = pos[e + k]; }
  else      { a = neg[k - e]; b = neg[e + (k - e)]; }
  const float4* ra = (const float4*)(z2 + (size_t)a*OUT_CH);
  const float4* rb = (const float4*)(z2 + (size_t)b*OUT_CH);
  float4 xa = ra[sub], xb = rb[sub];
  float s = xa.x*xb.x + xa.y*xb.y + xa.z*xb.z + xa.w*xb.w;
  #pragma unroll
  for (int m = 8; m >= 1; m >>= 1) s += __shfl_xor(s, m, 64);
  if (sub == 0) out[k] = s;
}

extern "C" void kernel_launch(void* const* d_in, const int* in_sizes, int n_in,
                              void* d_out, int out_size, void* d_ws, size_t ws_size,
                              hipStream_t stream) {
  const float* x        = (const float*)d_in[0];
  const int*   pos      = (const int*)d_in[1];
  const int*   neg      = (const int*)d_in[2];
  const float* W1       = (const float*)d_in[3];
  const float* att_src1 = (const float*)d_in[4];
  const float* att_dst1 = (const float*)d_in[5];
  const float* b1       = (const float*)d_in[6];
  const float* W2       = (const float*)d_in[7];
  const float* att_src2 = (const float*)d_in[8];
  const float* att_dst2 = (const float*)d_in[9];
  const float* b2       = (const float*)d_in[10];
  float* out = (float*)d_out;

  const int N = in_sizes[0] / IN_CH;   // 50000
  const int E = in_sizes[1] / 2;       // 800000

  char* w = (char*)d_ws;
  ushort* h1b = (ushort*)w;  w += (size_t)N*C1*2;
  ushort* z1b = (ushort*)w;  w += (size_t)N*C1*2;
  ushort* h2b = (ushort*)w;  w += (size_t)N*OUT_CH*2;
  ushort* xb  = (ushort*)w;  w += (size_t)N*IN_CH*2;
  float* z2v  = (float*)w;   w += (size_t)N*OUT_CH*4;
  float* aw   = (float*)w;   w += (size_t)E*4*4;      // also reused as aw2
  float* as1  = (float*)w;   w += (size_t)N*4*4;
  float* ad1  = (float*)w;   w += (size_t)N*4*4;
  float* as2  = (float*)w;   w += (size_t)N*4;
  float* ad2  = (float*)w;   w += (size_t)N*4;
  ushort* W1t = (ushort*)w;  w += (size_t)C1*IN_CH*2;
  ushort* W2t = (ushort*)w;  w += (size_t)OUT_CH*C1*2;
  int* deg    = (int*)w;     w += (size_t)N*4;
  int* rowptr = (int*)w;     w += (size_t)(N+1)*4;
  int* cursor = (int*)w;     w += (size_t)N*4;
  int* bsum   = (int*)w;     w += (size_t)256*4;
  int* csrc   = (int*)w;     w += (size_t)E*4;

  int eb = (E + 255)/256;
  int nb = (N + 255)/256;
  const int* pdst = pos + E;

  k_zero<<<nb, 256, 0, stream>>>(deg, cursor, N);
  k_hist<<<eb, 256, 0, stream>>>(pdst, deg, E);
  k_blocksum<<<nb, 256, 0, stream>>>(deg, bsum, N);
  k_scanb<<<1, 256, 0, stream>>>(bsum, nb);
  k_scanfinal<<<nb, 256, 0, stream>>>(deg, bsum, rowptr, N);
  k_scatter<<<eb, 256, 0, stream>>>(pos, pdst, rowptr, cursor, csrc, E);

  k_castx<<<((N*IN_CH/4) + 255)/256, 256, 0, stream>>>((const float4*)x, xb, N*IN_CH/4);
  k_tw<<<(IN_CH*C1 + 255)/256, 256, 0, stream>>>(W1, W1t, IN_CH, C1);
  k_tw<<<(C1*OUT_CH + 255)/256, 256, 0, stream>>>(W2, W2t, C1, OUT_CH);

  {
    dim3 g(C1/128, (N + 127)/128);
    k_gemm_bf16<128><<<g, 256, 0, stream>>>(xb, W1t, h1b, N, C1, IN_CH);
  }
  k_att1<<<N, 256, 0, stream>>>(h1b, att_src1, att_dst1, as1, ad1, N);
  k_agg1<<<N, 256, 0, stream>>>(h1b, as1, ad1, rowptr, csrc, b1, aw, (__hip_bfloat16*)z1b, N);

  {
    dim3 g(OUT_CH/64, (N + 127)/128);
    k_gemm_bf16<64><<<g, 256, 0, stream>>>(z1b, W2t, h2b, N, OUT_CH, C1);
  }
  k_att2<<<(N + 3)/4, 256, 0, stream>>>(h2b, att_src2, att_dst2, as2, ad2, N);
  k_agg2<<<N, 64, 0, stream>>>(h2b, as2, ad2, rowptr, csrc, b2, aw, z2v, N);

  k_decode<<<((size_t)2*E*16 + 255)/256, 256, 0, stream>>>(z2v, pos, neg, out, E);
}

// Round 4
// 452.212 us; speedup vs baseline: 1.5560x; 1.0594x over previous
//
#include <hip/hip_runtime.h>
#include <hip/hip_bf16.h>
#include <math.h>

#define IN_CH 128
#define HID 64
#define HEADS 4
#define C1 (HEADS*HID)   // 256
#define OUT_CH 64

typedef __attribute__((ext_vector_type(8))) short short8v;
typedef __attribute__((ext_vector_type(4))) float f32x4;

__device__ __forceinline__ float lrelu(float x){ return x > 0.f ? x : 0.2f*x; }

__device__ __forceinline__ ushort f2b(float f){
  unsigned u = __builtin_bit_cast(unsigned, f);
  unsigned r = (u + 0x7FFF + ((u>>16)&1)) >> 16;
  return (ushort)r;
}
__device__ __forceinline__ float b2f(ushort b){
  unsigned u = ((unsigned)b) << 16;
  return __builtin_bit_cast(float, u);
}

__device__ __forceinline__ float wsum64(float v){
  #pragma unroll
  for (int m = 32; m >= 1; m >>= 1) v += __shfl_xor(v, m, 64);
  return v;
}
__device__ __forceinline__ float wmax64(float v){
  #pragma unroll
  for (int m = 32; m >= 1; m >>= 1) v = fmaxf(v, __shfl_xor(v, m, 64));
  return v;
}

// ---------------- CSR build ----------------

__global__ void k_zero(int* a, int* b, int n){
  int i = blockIdx.x*256 + threadIdx.x;
  if (i < n){ a[i] = 0; b[i] = 0; }
}

__global__ void k_hist(const int* __restrict__ dst, int* deg, int e){
  int i = blockIdx.x*256 + threadIdx.x;
  if (i < e) atomicAdd(&deg[dst[i]], 1);
}

__global__ void k_blocksum(const int* __restrict__ deg, int* bsum, int n){
  __shared__ int buf[256];
  int b = blockIdx.x, tid = threadIdx.x;
  int i = b*256 + tid;
  buf[tid] = (i < n) ? deg[i] : 0;
  __syncthreads();
  for (int off = 128; off > 0; off >>= 1){
    if (tid < off) buf[tid] += buf[tid + off];
    __syncthreads();
  }
  if (tid == 0) bsum[b] = buf[0];
}

__global__ void k_scanb(int* bsum, int nb){
  __shared__ int buf[256];
  int tid = threadIdx.x;
  int v = (tid < nb) ? bsum[tid] : 0;
  buf[tid] = v;
  __syncthreads();
  for (int off = 1; off < 256; off <<= 1){
    int t = (tid >= off) ? buf[tid - off] : 0;
    __syncthreads();
    buf[tid] += t;
    __syncthreads();
  }
  if (tid < nb) bsum[tid] = buf[tid] - v;
}

__global__ void k_scanfinal(const int* __restrict__ deg, const int* __restrict__ bsum,
                            int* rowptr, int n){
  __shared__ int buf[256];
  int b = blockIdx.x, tid = threadIdx.x;
  int i = b*256 + tid;
  int v = (i < n) ? deg[i] : 0;
  buf[tid] = v;
  __syncthreads();
  for (int off = 1; off < 256; off <<= 1){
    int t = (tid >= off) ? buf[tid - off] : 0;
    __syncthreads();
    buf[tid] += t;
    __syncthreads();
  }
  if (i < n) rowptr[i + 1] = bsum[b] + buf[tid];
  if (b == 0 && tid == 0) rowptr[0] = 0;
}

__global__ void k_scatter(const int* __restrict__ src, const int* __restrict__ dst,
                          const int* __restrict__ rowptr, int* cursor, int* csrc, int e){
  int i = blockIdx.x*256 + threadIdx.x;
  if (i < e){
    int d = dst[i];
    int slot = rowptr[d] + atomicAdd(&cursor[d], 1);
    csrc[slot] = src[i];
  }
}

// ---------------- casts & weight folds ----------------

__global__ void k_castx(const float4* __restrict__ in, ushort* __restrict__ out, int n4){
  int i = blockIdx.x*256 + threadIdx.x;
  if (i < n4){
    float4 v = in[i];
    ushort4 o;
    o.x = f2b(v.x); o.y = f2b(v.y); o.z = f2b(v.z); o.w = f2b(v.w);
    *(ushort4*)(out + (size_t)i*4) = o;
  }
}

// W [K][N] f32 -> Wt [N][K] bf16
__global__ void k_tw(const float* __restrict__ W, ushort* __restrict__ Wt, int K, int N){
  int i = blockIdx.x*256 + threadIdx.x;
  if (i < K*N){
    int k = i / N, c = i - k*N;
    Wt[(size_t)c*K + k] = f2b(W[i]);
  }
}

// was4[c*4+h] = sum_j W1[c][h*64+j]*att_src1[h][j]; wad4 likewise. 512 threads.
__global__ void k_fold1(const float* __restrict__ W1, const float* __restrict__ as_v,
                        const float* __restrict__ ad_v, float* was4, float* wad4){
  int tid = threadIdx.x;           // 0..511 = c*4+h
  int c = tid >> 2, h = tid & 3;
  float s = 0.f, d = 0.f;
  for (int j = 0; j < HID; ++j){
    float w = W1[c*C1 + h*HID + j];
    s += w * as_v[h*HID + j];
    d += w * ad_v[h*HID + j];
  }
  was4[tid] = s; wad4[tid] = d;
}

// w2s[c] = sum_o W2[c][o]*att_src2[o]; 256 threads.
__global__ void k_fold2(const float* __restrict__ W2, const float* __restrict__ as_v,
                        const float* __restrict__ ad_v, float* w2s, float* w2d){
  int c = threadIdx.x;             // 0..255
  float s = 0.f, d = 0.f;
  for (int o = 0; o < OUT_CH; ++o){
    float w = W2[c*OUT_CH + o];
    s += w * as_v[o];
    d += w * ad_v[o];
  }
  w2s[c] = s; w2d[c] = d;
}

// as1/ad1 directly from x: wave per node, lane = 2 channels
__global__ __launch_bounds__(64) void k_fatt1(const ushort* __restrict__ xb,
    const float* __restrict__ was4, const float* __restrict__ wad4,
    float* __restrict__ as1, float* __restrict__ ad1, int n){
  int i = blockIdx.x;
  int l = threadIdx.x;
  ushort2 u = *(const ushort2*)(xb + (size_t)i*IN_CH + 2*l);
  float v0 = b2f(u.x), v1 = b2f(u.y);
  f32x4 s0 = *(const f32x4*)(was4 + 8*l);
  f32x4 s1 = *(const f32x4*)(was4 + 8*l + 4);
  f32x4 d0 = *(const f32x4*)(wad4 + 8*l);
  f32x4 d1 = *(const f32x4*)(wad4 + 8*l + 4);
  f32x4 ps, pd;
  #pragma unroll
  for (int h = 0; h < 4; ++h){
    ps[h] = wsum64(v0*s0[h] + v1*s1[h]);
    pd[h] = wsum64(v0*d0[h] + v1*d1[h]);
  }
  if (l == 0){
    *(f32x4*)(as1 + 4*i) = ps;
    *(f32x4*)(ad1 + 4*i) = pd;
  }
}

// as2/ad2 from z1: wave per node, lane = 4 channels
__global__ __launch_bounds__(64) void k_fatt2(const ushort* __restrict__ z1b,
    const float* __restrict__ w2s, const float* __restrict__ w2d,
    float* __restrict__ as2, float* __restrict__ ad2, int n){
  int i = blockIdx.x;
  int l = threadIdx.x;
  ushort4 u = *(const ushort4*)(z1b + (size_t)i*C1 + 4*l);
  float v0 = b2f(u.x), v1 = b2f(u.y), v2 = b2f(u.z), v3 = b2f(u.w);
  f32x4 s = *(const f32x4*)(w2s + 4*l);
  f32x4 d = *(const f32x4*)(w2d + 4*l);
  float ps = wsum64(v0*s[0] + v1*s[1] + v2*s[2] + v3*s[3]);
  float pd = wsum64(v0*d[0] + v1*d[1] + v2*d[2] + v3*d[3]);
  if (l == 0){ as2[i] = ps; ad2[i] = pd; }
}

// ---------------- conv1 aggregation in x-space: wave per node ----------------
// out: xagg[i][h][128] bf16 = sum_e w_e^h * x[src_e] (+ self)
__global__ __launch_bounds__(64) void k_xagg(
    const ushort* __restrict__ xb, const float* __restrict__ as1,
    const float* __restrict__ ad1, const int* __restrict__ rowptr,
    const int* __restrict__ csrc, float* __restrict__ aw,
    ushort* __restrict__ xagg, int n)
{
  int i = blockIdx.x;
  int l = threadIdx.x;
  int beg = rowptr[i], end = rowptr[i+1];
  f32x4 ad4 = *(const f32x4*)(ad1 + 4*i);

  // phase A: alpha + online max/denom, all 4 heads per lane
  f32x4 m = (f32x4)(-1e30f), s = (f32x4)(0.f);
  for (int sl = beg + l; sl < end; sl += 64){
    int sj = csrc[sl];
    f32x4 a4 = *(const f32x4*)(as1 + 4*sj);
    f32x4 al;
    #pragma unroll
    for (int h = 0; h < 4; ++h){
      float a = lrelu(a4[h] + ad4[h]);
      al[h] = a;
      if (a <= m[h]) s[h] += expf(a - m[h]);
      else { s[h] = s[h]*expf(m[h] - a) + 1.f; m[h] = a; }
    }
    *(f32x4*)(aw + 4*(size_t)sl) = al;
  }
  f32x4 asf = *(const f32x4*)(as1 + 4*i);
  f32x4 M2, rd, wself;
  #pragma unroll
  for (int h = 0; h < 4; ++h){
    float M = wmax64(m[h]);
    float S = wsum64(s[h] * expf(m[h] - M));
    float aself = lrelu(asf[h] + ad4[h]);
    float Mx = fmaxf(M, aself);
    S = S * expf(M - Mx);
    float es = expf(aself - Mx);
    S += es;
    float r = 1.f / (S + 1e-16f);
    M2[h] = Mx; rd[h] = r; wself[h] = es * r;
  }

  // phase B: lane owns channels 2l, 2l+1; acc[h][2]
  ushort2 us = *(const ushort2*)(xb + (size_t)i*IN_CH + 2*l);
  float x0 = b2f(us.x), x1 = b2f(us.y);
  float acc0[4], acc1[4];
  #pragma unroll
  for (int h = 0; h < 4; ++h){ acc0[h] = wself[h]*x0; acc1[h] = wself[h]*x1; }

  int e = beg;
  for (; e + 1 < end; e += 2){
    int s0 = csrc[e], s1 = csrc[e+1];
    f32x4 A0 = *(const f32x4*)(aw + 4*(size_t)e);
    f32x4 A1 = *(const f32x4*)(aw + 4*(size_t)(e+1));
    ushort2 u0 = *(const ushort2*)(xb + (size_t)s0*IN_CH + 2*l);
    ushort2 u1 = *(const ushort2*)(xb + (size_t)s1*IN_CH + 2*l);
    float a0 = b2f(u0.x), b0 = b2f(u0.y);
    float a1 = b2f(u1.x), b1v = b2f(u1.y);
    #pragma unroll
    for (int h = 0; h < 4; ++h){
      float w0 = expf(A0[h] - M2[h]) * rd[h];
      float w1 = expf(A1[h] - M2[h]) * rd[h];
      acc0[h] += w0*a0 + w1*a1;
      acc1[h] += w0*b0 + w1*b1v;
    }
  }
  if (e < end){
    int s0 = csrc[e];
    f32x4 A0 = *(const f32x4*)(aw + 4*(size_t)e);
    ushort2 u0 = *(const ushort2*)(xb + (size_t)s0*IN_CH + 2*l);
    float a0 = b2f(u0.x), b0 = b2f(u0.y);
    #pragma unroll
    for (int h = 0; h < 4; ++h){
      float w0 = expf(A0[h] - M2[h]) * rd[h];
      acc0[h] += w0*a0;
      acc1[h] += w0*b0;
    }
  }
  #pragma unroll
  for (int h = 0; h < 4; ++h){
    ushort2 o; o.x = f2b(acc0[h]); o.y = f2b(acc1[h]);
    *(ushort2*)(xagg + (size_t)i*512 + h*128 + 2*l) = o;
  }
}

// ---------------- bf16 MFMA GEMM, BM=128, BN=64, BK=64, strided, batched-z ----
template<bool RELU_BIAS>
__global__ __launch_bounds__(256) void k_gemm2(
    const ushort* __restrict__ A, const ushort* __restrict__ Bt,
    ushort* __restrict__ Cb, const float* __restrict__ bias,
    int M, int K, int lda, int ldc, int aZ, int bZ, int cZ)
{
  constexpr int BM = 128, BN = 64, NF = 2;
  __shared__ uint4 As[BM*8];
  __shared__ uint4 Bs[BN*8];
  int tid = threadIdx.x;
  int wave = tid >> 6, lane = tid & 63;
  int wr = wave >> 1, wc = wave & 1;
  int bm = blockIdx.y * BM;
  int z = blockIdx.z;
  const ushort* Az = A + (size_t)z*aZ;
  const ushort* Bz = Bt + (size_t)z*bZ;
  int g = lane >> 4, lr = lane & 15;

  f32x4 acc[4][NF];
  #pragma unroll
  for (int m = 0; m < 4; ++m)
    #pragma unroll
    for (int n = 0; n < NF; ++n) acc[m][n] = (f32x4)(0.f);

  for (int k0 = 0; k0 < K; k0 += 64){
    for (int idx = tid; idx < BM*8; idx += 256){
      int r = idx >> 3, c = idx & 7;
      int gr = bm + r;
      uint4 v = make_uint4(0u,0u,0u,0u);
      if (gr < M) v = *(const uint4*)(Az + (size_t)gr*lda + k0 + c*8);
      As[r*8 + (c ^ (r & 7))] = v;
    }
    for (int idx = tid; idx < BN*8; idx += 256){
      int r = idx >> 3, c = idx & 7;
      uint4 v = *(const uint4*)(Bz + (size_t)r*K + k0 + c*8);
      Bs[r*8 + (c ^ (r & 7))] = v;
    }
    __syncthreads();
    #pragma unroll
    for (int kk = 0; kk < 2; ++kk){
      short8v af[4], bf[NF];
      #pragma unroll
      for (int m = 0; m < 4; ++m){
        int r = wr*64 + m*16 + lr;
        int c = kk*4 + g;
        af[m] = *(const short8v*)&As[r*8 + (c ^ (r & 7))];
      }
      #pragma unroll
      for (int n = 0; n < NF; ++n){
        int r = wc*32 + n*16 + lr;
        int c = kk*4 + g;
        bf[n] = *(const short8v*)&Bs[r*8 + (c ^ (r & 7))];
      }
      #pragma unroll
      for (int m = 0; m < 4; ++m)
        #pragma unroll
        for (int n = 0; n < NF; ++n)
          acc[m][n] = __builtin_amdgcn_mfma_f32_16x16x32_bf16(af[m], bf[n], acc[m][n], 0, 0, 0);
    }
    __syncthreads();
  }
  #pragma unroll
  for (int m = 0; m < 4; ++m){
    #pragma unroll
    for (int q = 0; q < 4; ++q){
      int row = bm + wr*64 + m*16 + g*4 + q;
      if (row < M){
        #pragma unroll
        for (int n = 0; n < NF; ++n){
          int col = wc*32 + n*16 + lr;
          float v = acc[m][n][q];
          if (RELU_BIAS) v = fmaxf(v + bias[cZ*z + col], 0.f);
          Cb[(size_t)row*ldc + cZ*z + col] = f2b(v);
        }
      }
    }
  }
}

// ---------------- conv2 aggregation: wave per node, 2 edges/iter ----------------
__global__ __launch_bounds__(64) void k_hagg(
    const ushort* __restrict__ h2b, const float* __restrict__ as2,
    const float* __restrict__ ad2, const int* __restrict__ rowptr,
    const int* __restrict__ csrc, const float* __restrict__ b2,
    float* __restrict__ aw2, ushort* __restrict__ z2b, int n)
{
  int i = blockIdx.x;
  int l = threadIdx.x;
  int beg = rowptr[i], end = rowptr[i+1];
  float adv = ad2[i];

  float m = -1e30f, s = 0.f;
  for (int sl = beg + l; sl < end; sl += 64){
    float a = lrelu(as2[csrc[sl]] + adv);
    aw2[sl] = a;
    if (a <= m) s += expf(a - m);
    else { s = s*expf(m - a) + 1.f; m = a; }
  }
  float M = wmax64(m);
  float S = wsum64(s * expf(m - M));
  float aself = lrelu(as2[i] + adv);
  float M2 = fmaxf(M, aself);
  S = S * expf(M - M2);
  float es = expf(aself - M2);
  S += es;
  float rd = 1.f / (S + 1e-16f);
  float wself = es * rd;

  int half = l >> 5;          // 0 or 1
  int c2 = (l & 31) * 2;      // channel pair
  float acc0 = 0.f, acc1 = 0.f;
  if (half == 0){
    ushort2 u = *(const ushort2*)(h2b + (size_t)i*OUT_CH + c2);
    acc0 = wself * b2f(u.x);
    acc1 = wself * b2f(u.y);
  }
  for (int e = beg + half; e < end; e += 2){
    int sj = csrc[e];
    float w = expf(aw2[e] - M2) * rd;
    ushort2 u = *(const ushort2*)(h2b + (size_t)sj*OUT_CH + c2);
    acc0 += w * b2f(u.x);
    acc1 += w * b2f(u.y);
  }
  acc0 += __shfl_xor(acc0, 32, 64);
  acc1 += __shfl_xor(acc1, 32, 64);
  if (half == 0){
    ushort2 o;
    o.x = f2b(acc0 + b2[c2]);
    o.y = f2b(acc1 + b2[c2+1]);
    *(ushort2*)(z2b + (size_t)i*OUT_CH + c2) = o;
  }
}

// ---------------- decoder: 2-pass channel-split, 8 lanes/edge ----------------
template<int PASS>
__global__ void k_dec(const ushort* __restrict__ z2b, const int* __restrict__ pos,
                      const int* __restrict__ neg, float* __restrict__ part,
                      float* __restrict__ out, int e){
  int g = blockIdx.x*256 + threadIdx.x;
  int k = g >> 3;
  int sub = g & 7;
  if (k >= 2*e) return;
  int a, b;
  if (k < e){ a = pos[k];     b = pos[e + k]; }
  else      { a = neg[k - e]; b = neg[e + (k - e)]; }
  ushort4 ua = *(const ushort4*)(z2b + (size_t)a*OUT_CH + PASS*32 + sub*4);
  ushort4 ub = *(const ushort4*)(z2b + (size_t)b*OUT_CH + PASS*32 + sub*4);
  float p = b2f(ua.x)*b2f(ub.x) + b2f(ua.y)*b2f(ub.y)
          + b2f(ua.z)*b2f(ub.z) + b2f(ua.w)*b2f(ub.w);
  #pragma unroll
  for (int mm = 4; mm >= 1; mm >>= 1) p += __shfl_xor(p, mm, 64);
  if (sub == 0){
    if (PASS == 0) part[k] = p;
    else           out[k] = part[k] + p;
  }
}

extern "C" void kernel_launch(void* const* d_in, const int* in_sizes, int n_in,
                              void* d_out, int out_size, void* d_ws, size_t ws_size,
                              hipStream_t stream) {
  const float* x        = (const float*)d_in[0];
  const int*   pos      = (const int*)d_in[1];
  const int*   neg      = (const int*)d_in[2];
  const float* W1       = (const float*)d_in[3];
  const float* att_src1 = (const float*)d_in[4];
  const float* att_dst1 = (const float*)d_in[5];
  const float* b1       = (const float*)d_in[6];
  const float* W2       = (const float*)d_in[7];
  const float* att_src2 = (const float*)d_in[8];
  const float* att_dst2 = (const float*)d_in[9];
  const float* b2       = (const float*)d_in[10];
  float* out = (float*)d_out;

  const int N = in_sizes[0] / IN_CH;   // 50000
  const int E = in_sizes[1] / 2;       // 800000

  char* w = (char*)d_ws;
  ushort* xb   = (ushort*)w;  w += (size_t)N*IN_CH*2;
  ushort* xagg = (ushort*)w;  w += (size_t)N*512*2;          // 51.2MB; sub-reused below
  ushort* z1b  = (ushort*)w;  w += (size_t)N*C1*2;
  float* aw    = (float*)w;   w += (size_t)E*4*4;            // conv1 alpha; reused as aw2
  float* as1   = (float*)w;   w += (size_t)N*4*4;
  float* ad1   = (float*)w;   w += (size_t)N*4*4;
  float* as2   = (float*)w;   w += (size_t)N*4;
  float* ad2   = (float*)w;   w += (size_t)N*4;
  ushort* W1t  = (ushort*)w;  w += (size_t)C1*IN_CH*2;
  ushort* W2t  = (ushort*)w;  w += (size_t)OUT_CH*C1*2;
  float* was4  = (float*)w;   w += 512*4;
  float* wad4  = (float*)w;   w += 512*4;
  float* w2s   = (float*)w;   w += 256*4;
  float* w2d   = (float*)w;   w += 256*4;
  int* deg     = (int*)w;     w += (size_t)N*4;
  int* rowptr  = (int*)w;     w += (size_t)(N+1)*4;
  int* cursor  = (int*)w;     w += (size_t)N*4;
  int* bsum    = (int*)w;     w += (size_t)256*4;
  int* csrc    = (int*)w;     w += (size_t)E*4;

  // sub-allocations inside xagg (dead after z1 GEMM):
  ushort* h2b = xagg;                              // N*64*2 = 6.4MB
  ushort* z2b = xagg + (size_t)N*OUT_CH;           // 6.4MB
  float*  part = (float*)(xagg + (size_t)2*N*OUT_CH);  // 2E*4 = 6.4MB

  int eb = (E + 255)/256;
  int nb = (N + 255)/256;
  const int* pdst = pos + E;

  k_zero<<<nb, 256, 0, stream>>>(deg, cursor, N);
  k_hist<<<eb, 256, 0, stream>>>(pdst, deg, E);
  k_blocksum<<<nb, 256, 0, stream>>>(deg, bsum, N);
  k_scanb<<<1, 256, 0, stream>>>(bsum, nb);
  k_scanfinal<<<nb, 256, 0, stream>>>(deg, bsum, rowptr, N);
  k_scatter<<<eb, 256, 0, stream>>>(pos, pdst, rowptr, cursor, csrc, E);

  k_castx<<<((N*IN_CH/4) + 255)/256, 256, 0, stream>>>((const float4*)x, xb, N*IN_CH/4);
  k_tw<<<(IN_CH*C1 + 255)/256, 256, 0, stream>>>(W1, W1t, IN_CH, C1);
  k_tw<<<(C1*OUT_CH + 255)/256, 256, 0, stream>>>(W2, W2t, C1, OUT_CH);
  k_fold1<<<1, 512, 0, stream>>>(W1, att_src1, att_dst1, was4, wad4);
  k_fold2<<<1, 256, 0, stream>>>(W2, att_src2, att_dst2, w2s, w2d);

  k_fatt1<<<N, 64, 0, stream>>>(xb, was4, wad4, as1, ad1, N);
  k_xagg<<<N, 64, 0, stream>>>(xb, as1, ad1, rowptr, csrc, aw, xagg, N);

  {  // z1 = relu(blockdiag(xagg_h @ W1_h) + b1), 4 heads via blockIdx.z
    dim3 g(1, (N + 127)/128, 4);
    k_gemm2<true><<<g, 256, 0, stream>>>(xagg, W1t, z1b, b1,
        N, IN_CH, 512, C1, IN_CH, OUT_CH*IN_CH, OUT_CH);
  }
  k_fatt2<<<N, 64, 0, stream>>>(z1b, w2s, w2d, as2, ad2, N);

  {  // h2 = z1 @ W2
    dim3 g(1, (N + 127)/128, 1);
    k_gemm2<false><<<g, 256, 0, stream>>>(z1b, W2t, h2b, nullptr,
        N, C1, C1, OUT_CH, 0, 0, 0);
  }
  k_hagg<<<N, 64, 0, stream>>>(h2b, as2, ad2, rowptr, csrc, b2, aw, z2b, N);

  int db = (int)(((size_t)2*E*8 + 255)/256);
  k_dec<0><<<db, 256, 0, stream>>>(z2b, pos, neg, part, out, E);
  k_dec<1><<<db, 256, 0, stream>>>(z2b, pos, neg, part, out, E);
}